// Round 8
// baseline (164.885 us; speedup 1.0000x reference)
//
#include <hip/hip_runtime.h>
#include <stdint.h>

typedef short v8s __attribute__((ext_vector_type(8)));
typedef float v4f __attribute__((ext_vector_type(4)));

#define KS    7
#define KPTS  9
#define OCH   128
#define CCH   128
#define NB    32
#define HW    56
#define PAD   3

#define HBLK  8
#define ROWS  14            // HBLK + 6
#define WP    72
#define CCK   32
#define NCC   4
#define HP    62
#define ROWB  (WP*CCK*2)        // 4608 B per padded x_t row
#define XS_B  (ROWS*WP*CCK*2)   // 64512 B = 63 KB-lines
#define AB_B  (8*OCH*CCK*2)     // 65536 B (ring of 8 A-slots)
#define SMEM_B (XS_B + AB_B)    // 130048 B -> 1 block/CU

__device__ __forceinline__ unsigned short f2bf(float f) {
  unsigned int u = __builtin_bit_cast(unsigned int, f);
  u += 0x7fffu + ((u >> 16) & 1u);
  return (unsigned short)(u >> 16);
}

__device__ __forceinline__ void gl_lds16(const void* g, void* l) {
  __builtin_amdgcn_global_load_lds(
      (const __attribute__((address_space(1))) unsigned int*)g,
      (__attribute__((address_space(3))) unsigned int*)l, 16, 0, 0);
}

// Kernel construction: block = c (128), thread = o (128). Private 49-float row
// in LDS -> no atomics. kb [cc][tap][o][c32] bf16, A-swizzle baked
// (chunk ^ ((o>>1)&3)).
__global__ __launch_bounds__(128) void build_kern(
    const float* __restrict__ wgt, const float* __restrict__ P,
    unsigned short* __restrict__ kb) {
  __shared__ float sm[OCH*49];
  const int c = blockIdx.x, o = threadIdx.x;
  float* mine = &sm[o*49];
  #pragma unroll
  for (int j = 0; j < 49; ++j) mine[j] = 0.f;
  for (int k = 0; k < KPTS; ++k) {
    const float ph = fminf(fmaxf(P[c*KPTS + k], -3.f), 3.f) + 3.f;
    const float pw = fminf(fmaxf(P[CCH*KPTS + c*KPTS + k], -3.f), 3.f) + 3.f;
    const int ih = (int)floorf(ph), iw = (int)floorf(pw);
    const float rh = ph - (float)ih, rw = pw - (float)iw;
    const float wt = wgt[(o*CCH + c)*KPTS + k];
    mine[ih*KS + iw] += wt*(1.f-rh)*(1.f-rw);
    if (iw+1 < KS) mine[ih*KS + iw+1] += wt*(1.f-rh)*rw;
    if (ih+1 < KS) mine[(ih+1)*KS + iw] += wt*rh*(1.f-rw);
    if (ih+1 < KS && iw+1 < KS) mine[(ih+1)*KS + iw+1] += wt*rh*rw;
  }
  const int cc = c >> 5, sc = (c >> 3) & 3, cl = c & 7;
  const int pc = sc ^ ((o >> 1) & 3);
  for (int tap = 0; tap < 49; ++tap)
    kb[(((size_t)(cc*49 + tap)*OCH + o)*CCK) + pc*8 + cl] = f2bf(mine[tap]);
}

// x [n][c][h][w] f32 -> x_t [n][cc][h'][w'][c32] bf16, pads baked as zeros,
// B-swizzle baked: data chunk s stored at phys chunk s ^ ((w'>>1)&3).
__global__ __launch_bounds__(256) void xpose(const float* __restrict__ x,
                                             unsigned short* __restrict__ xt) {
  __shared__ unsigned short lb[CCK][HW + 2];
  const int hp = blockIdx.x;
  const int cc = blockIdx.y;
  const int n  = blockIdx.z;
  const int t  = threadIdx.x;
  const int h  = hp - PAD;
  const bool valid = (unsigned)h < (unsigned)HW;
  if (valid) {
    const float* xb = x + ((size_t)(n*CCH + cc*CCK)*HW + h)*HW;
    #pragma unroll
    for (int k = 0; k < 7; ++k) {
      const int j = k*256 + t;
      const int c = j / HW, w = j % HW;
      lb[c][w] = f2bf(xb[(size_t)c*HW*HW + w]);
    }
  }
  __syncthreads();
  unsigned short* orow = xt + (size_t)((n*NCC + cc)*HP + hp)*(WP*CCK);
  for (int q = t; q < WP*4; q += 256) {
    const int wq = q >> 2, pc = q & 3;
    const int s  = pc ^ ((wq >> 1) & 3);
    v8s v = (v8s){0,0,0,0,0,0,0,0};
    const int w = wq - PAD;
    if (valid && (unsigned)w < (unsigned)HW) {
      #pragma unroll
      for (int jj = 0; jj < 8; ++jj) v[jj] = (short)lb[s*8 + jj][w];
    }
    *(v8s*)&orow[wq*CCK + pc*8] = v;
  }
}

// Prefetch tap T's 12 fragments (8 A from ring slot T&7, 4 B from xs) into regs.
#define PF_FRAGS(T, FA, FB)                                                   \
  {                                                                           \
    const int kh = (T)/7, kw = (T) - kh*7;                                    \
    const int r = wv + kh;                                                    \
    const unsigned short* ap = ab + (size_t)((T) & 7)*(OCH*CCK);              \
    _Pragma("unroll")                                                         \
    for (int mt = 0; mt < 8; ++mt)                                            \
      FA[mt] = *(const v8s*)&ap[(mt*16 + col)*CCK + swA];                     \
    _Pragma("unroll")                                                         \
    for (int nt = 0; nt < 4; ++nt) {                                          \
      const int wp = nt*16 + col + kw;                                        \
      FB[nt] = *(const v8s*)&xs[(r*WP + wp)*CCK +                             \
                                ((kgrp ^ ((wp >> 1) & 3)) << 3)];             \
    }                                                                         \
  }

#define MFMA_ONLY(FA, FB)                                                     \
  {                                                                           \
    __builtin_amdgcn_s_setprio(1);                                            \
    _Pragma("unroll")                                                         \
    for (int nt = 0; nt < 4; ++nt)                                            \
      _Pragma("unroll")                                                       \
      for (int mt = 0; mt < 8; ++mt)                                          \
        acc[mt][nt] = __builtin_amdgcn_mfma_f32_16x16x32_bf16(                \
            FA[mt], FB[nt], acc[mt][nt], 0, 0, 0);                            \
    __builtin_amdgcn_s_setprio(0);                                            \
  }

// Conv: grid 32 x 7 = 224 blocks (1/CU). 512 thr = 8 waves, wave = one h-row,
// per-wave tile M=128(o) x N=64(w), 16x16x32 MFMA.
// 4-tap phases on an 8-slot A-ring + register double-banked fragments:
// tap T+1's ds_reads issue BEFORE tap T's MFMA burst (counted lgkmcnt),
// so the LDS pipe runs under the matrix pipe. One vmcnt(0)+barrier per phase.
__global__ __launch_bounds__(512, 2) void dcls_conv(
    const unsigned short* __restrict__ xt, const unsigned short* __restrict__ kb,
    const float* __restrict__ bias, float* __restrict__ out)
{
  extern __shared__ char smem[];
  unsigned short* xs = (unsigned short*)smem;            // [ROWS][WP][CCK]
  unsigned short* ab = (unsigned short*)(smem + XS_B);   // ring of 8 [OCH][CCK]

  const int n   = blockIdx.x;
  const int hb  = blockIdx.y;
  const int tid = threadIdx.x;
  const int lane = tid & 63;
  const int wv   = tid >> 6;        // 0..7 = h-row within block
  const int col  = lane & 15;
  const int kgrp = lane >> 4;
  const int swA  = (kgrp ^ ((col >> 1) & 3)) << 3;

  v4f acc[8][4];
  #pragma unroll
  for (int m = 0; m < 8; ++m)
    #pragma unroll
    for (int t = 0; t < 4; ++t)
      acc[m][t] = (v4f){0.f,0.f,0.f,0.f};

  v8s fa0[8], fa1[8], fb0[4], fb1[4];

  for (int cc = 0; cc < NCC; ++cc) {
    __syncthreads();   // all waves done reading previous cc's xs/ring
    // ---- stage xs: 63 linear KB-lines ----
    const char* src = (const char*)xt + (size_t)((n*NCC + cc)*HP + hb*HBLK)*ROWB;
    for (int i = wv; i < 63; i += 8)
      gl_lds16(src + i*1024 + lane*16, (char*)xs + i*1024);
    // ---- stage phase-0 A tiles (taps 0..3) ----
    const char* ks = (const char*)kb + (size_t)cc*49*8192;
    #pragma unroll
    for (int j = 0; j < 4; ++j)
      gl_lds16(ks + (size_t)j*8192 + wv*1024 + lane*16,
               (char*)ab + (size_t)j*8192 + wv*1024 + lane*16);
    asm volatile("s_waitcnt vmcnt(0)" ::: "memory");
    __builtin_amdgcn_s_barrier();

    PF_FRAGS(0, fa0, fb0)

    #pragma unroll 1
    for (int p = 0; p < 12; ++p) {
      const int tb = 4*p;
      // issue next phase's A-loads into the other ring bank (drained last barrier)
      #pragma unroll
      for (int j = 0; j < 4; ++j) {
        const int T = tb + 4 + j;
        if (T < 49)
          gl_lds16(ks + (size_t)T*8192 + wv*1024 + lane*16,
                   (char*)ab + (size_t)(T & 7)*8192 + wv*1024 + lane*16);
      }
      // pipelined compute: PF(T+1) under MFMA(T)
      PF_FRAGS(tb + 1, fa1, fb1)
      MFMA_ONLY(fa0, fb0)
      PF_FRAGS(tb + 2, fa0, fb0)
      MFMA_ONLY(fa1, fb1)
      PF_FRAGS(tb + 3, fa1, fb1)
      MFMA_ONLY(fa0, fb0)
      MFMA_ONLY(fa1, fb1)
      asm volatile("s_waitcnt vmcnt(0)" ::: "memory");
      __builtin_amdgcn_s_barrier();
      // post-barrier: first tap of next phase from freshly-landed slots
      PF_FRAGS(tb + 4, fa0, fb0)        // p=11 -> tap 48
    }
    MFMA_ONLY(fa0, fb0)                 // tap 48
  }

  // ---- epilogue: D row=(lane>>4)*4+reg, col=lane&15 ----
  const int h = hb*HBLK + wv;
  #pragma unroll
  for (int mt = 0; mt < 8; ++mt) {
    #pragma unroll
    for (int rr = 0; rr < 4; ++rr) {
      const int o = mt*16 + (lane >> 4)*4 + rr;
      const float bs = bias[o];
      #pragma unroll
      for (int nt = 0; nt < 4; ++nt) {
        const int w = nt*16 + col;
        if (w < HW)
          out[((size_t)(n*OCH + o)*HW + h)*HW + w] = acc[mt][nt][rr] + bs;
      }
    }
  }
}

extern "C" void kernel_launch(void* const* d_in, const int* in_sizes, int n_in,
                              void* d_out, int out_size, void* d_ws, size_t ws_size,
                              hipStream_t stream) {
  const float* x    = (const float*)d_in[0];
  const float* wgt  = (const float*)d_in[1];
  const float* P    = (const float*)d_in[2];
  const float* bias = (const float*)d_in[3];
  float* out = (float*)d_out;

  unsigned short* kb = (unsigned short*)d_ws;                       // 1.6 MB
  unsigned short* xt = (unsigned short*)((char*)d_ws + (2u<<20));   // 36.6 MB

  hipFuncSetAttribute((const void*)dcls_conv,
                      hipFuncAttributeMaxDynamicSharedMemorySize, SMEM_B);

  build_kern<<<CCH, OCH, 0, stream>>>(wgt, P, kb);
  xpose<<<dim3(HP, NCC, NB), 256, 0, stream>>>(x, xt);
  dcls_conv<<<dim3(NB, KS), 512, SMEM_B, stream>>>(xt, kb, bias, out);
}